// Round 5
// baseline (421.522 us; speedup 1.0000x reference)
//
#include <hip/hip_runtime.h>
#include <hip/hip_bf16.h>

#define NB 8192
#define ND 128
#define NC 10000
#define NMT 79                 // class tiles (128 wide), ceil(10000/128)
#define NCPAD (NMT * 128)      // 10112
#define BT 64                  // batch rows per GEMM block
#define SLICES 4               // class-tile slices per batch-tile
#define GRID ((NB / BT) * SLICES)  // 512 blocks = exactly 2/CU (8 waves/CU)

#define LOG2E 1.4426950408889634f
#define NLN2  (-0.6931471805599453f)

typedef short bfrag8 __attribute__((ext_vector_type(8)));  // 8 bf16 (4 VGPRs)
typedef float facc4 __attribute__((ext_vector_type(4)));   // MFMA C/D

__device__ __forceinline__ unsigned short f2bf(float f) {
  union { float f; unsigned u; } v; v.f = f;
  unsigned r = v.u + 0x7FFFu + ((v.u >> 16) & 1u);  // RNE
  return (unsigned short)(r >> 16);
}

// ===== fragment-order scratch layouts ====================================
// Both xb and Wt are stored as 16B fragment units so a GEMM fragment load
// is ONE coalesced 1KB global_load_dwordx4 (lane l reads base + l*16):
//   offset16B(strip s, kk, lane l) = s*256 + kk*64 + l
// where unit (s,kk,quad,l15) holds rows [s*16+l15], d [kk*32+quad*8 .. +8)
// -- exactly the mfma_f32_16x16x32_bf16 A/B fragment for K-slab kk.

// ---- prep: x->frag-bf16 | S=0 | W transpose+convert to frag order -------
// W and bias are pre-scaled by log2e so GEMM epilogues use native
// v_exp_f32/v_log_f32 (exp2/log2). Both passes see identical logits ->
// the exp term in -log(S - e) cancels exactly.
#define XJOBS 512              // one 16-row strip (256 16B units) per block
#define SJOBS 32               // 8192 / 256
#define WJOBS (316 * 4)        // (NCPAD/32) x (128/32) 32x32 transpose tiles
#define TOTJOBS (XJOBS + SJOBS + WJOBS)

__global__ void prep_kernel(const float* __restrict__ x,
                            const float* __restrict__ W,
                            unsigned short* __restrict__ xb,
                            unsigned short* __restrict__ Wt,
                            float* __restrict__ S) {
  int job = blockIdx.x, tid = threadIdx.x;
  if (job < XJOBS) {
    // strip sb=job; tid -> (kk=t>>6, quad=(t>>4)&3, l15=t&15); out unit
    // index = job*256 + tid exactly (layout identity). Read 8 floats of
    // row sb*16+l15, d = (kk*4+quad)*8 ..+8; write one 16B unit.
    int kk = tid >> 6, quad = (tid >> 4) & 3, l15 = tid & 15;
    int row = job * 16 + l15, chunk = kk * 4 + quad;
    const float4* xr = (const float4*)(x + (size_t)row * ND + chunk * 8);
    float4 a = xr[0], b = xr[1];
    ushort4 o0, o1;
    o0.x = f2bf(a.x); o0.y = f2bf(a.y); o0.z = f2bf(a.z); o0.w = f2bf(a.w);
    o1.x = f2bf(b.x); o1.y = f2bf(b.y); o1.z = f2bf(b.z); o1.w = f2bf(b.w);
    ushort4* op = (ushort4*)(xb + ((size_t)job * 256 + tid) * 8);
    op[0] = o0; op[1] = o1;
  } else if (job < XJOBS + SJOBS) {
    S[(job - XJOBS) * 256 + tid] = 0.f;      // ws is re-poisoned 0xAA
  } else {
    __shared__ float t[32][33];              // t[d_local][c_local]
    int j = job - XJOBS - SJOBS;
    int c0 = (j >> 2) * 32, r0 = (j & 3) * 32;   // classes c0.., d r0..
    int tx = tid & 31, ty = tid >> 5;        // (32, 8)
    #pragma unroll
    for (int i = 0; i < 4; ++i) {
      int r = r0 + ty + i * 8, c = c0 + tx;  // r < 128 always
      t[ty + i * 8][tx] = (c < NC) ? W[(size_t)r * NC + c] : 0.f;
    }
    __syncthreads();
    if (tid < 128) {
      // thread -> (c_local = tid>>2, ch_local = tid&3): gather 8 bf16 of
      // class c, d = r0 + ch*8 ..+8 -> one 16B frag-unit store.
      int c_local = tid >> 2, ch = tid & 3;
      int c = c0 + c_local;
      int s = c >> 4, l15 = c & 15;
      int kk = r0 >> 5, quad = ch;           // chunk = r0/8 + ch = kk*4+quad
      ushort4 o0, o1;
      float e0 = t[ch * 8 + 0][c_local] * LOG2E;
      float e1 = t[ch * 8 + 1][c_local] * LOG2E;
      float e2 = t[ch * 8 + 2][c_local] * LOG2E;
      float e3 = t[ch * 8 + 3][c_local] * LOG2E;
      float e4 = t[ch * 8 + 4][c_local] * LOG2E;
      float e5 = t[ch * 8 + 5][c_local] * LOG2E;
      float e6 = t[ch * 8 + 6][c_local] * LOG2E;
      float e7 = t[ch * 8 + 7][c_local] * LOG2E;
      o0.x = f2bf(e0); o0.y = f2bf(e1); o0.z = f2bf(e2); o0.w = f2bf(e3);
      o1.x = f2bf(e4); o1.y = f2bf(e5); o1.z = f2bf(e6); o1.w = f2bf(e7);
      ushort4* op = (ushort4*)(Wt + ((size_t)s * 256 + kk * 64 + quad * 16 + l15) * 8);
      op[0] = o0; op[1] = o1;
    }
  }
}

// ---- GEMM pass: ZERO LDS, ZERO barriers, register-streamed --------------
// Round-3/4 evidence: barrier-chained tile loop is serialization-bound
// (MfmaUtil 6.7 / VALU 23 / HBM 17 / occ 22 all low; occupancy bump was a
// no-op). Here each wave is fully independent: X operand (32 rows x 128 d
// = 32 VGPR) lives in registers for the whole kernel; W fragments stream
// through one 64-VGPR buffer, software-pipelined at kk granularity (next
// tile's kk-slab loads issue right after this tile's kk-slab MFMAs; WAR
// deps keep order, compiler emits exact counted waitcnts). Fragment loads
// are 1KB contiguous (frag-order layout), L2-resident (Wt = 2.59MB fits
// per-XCD L2). Stores fly until HBM backpressure -- no vmcnt(0) drains.
// Wave (wm,wn) owns 64 classes x 32 batch of the block's 128x64 tile.
template <int STATS>
__global__ __launch_bounds__(256, 2) void gemm_pass(
    const unsigned short* __restrict__ xb,   // frag-order bf16
    const unsigned short* __restrict__ Wt,   // frag-order bf16 (x log2e)
    const float* __restrict__ bias,          // [NC]
    float* __restrict__ S,                   // [NB]
    float* __restrict__ out) {               // [NB][NC]
  const int bid = blockIdx.x;
  const int slice = bid % SLICES, bt0 = (bid / SLICES) * BT;
  const int tid = threadIdx.x;
  const int w = tid >> 6, l = tid & 63;
  const int lane15 = l & 15, quad = l >> 4;
  const int wm = w >> 1, wn = w & 1;         // wm: class half, wn: batch half

  const bfrag8* xp = (const bfrag8*)xb;
  const bfrag8* wp = (const bfrag8*)Wt;

  // ---- X operand: resident in registers for the whole kernel ------------
  bfrag8 xf[2][4];
  #pragma unroll
  for (int tn = 0; tn < 2; ++tn) {
    int sx = (bt0 >> 4) + wn * 2 + tn;
    #pragma unroll
    for (int kk = 0; kk < 4; ++kk)
      xf[tn][kk] = xp[sx * 256 + kk * 64 + l];
  }

  float Sv[2];
  if (!STATS) {
    #pragma unroll
    for (int tn = 0; tn < 2; ++tn)
      Sv[tn] = S[bt0 + wn * 32 + tn * 16 + lane15];
  }

  // ---- preload first W tile ---------------------------------------------
  bfrag8 af[4][4];
  {
    int s0 = slice * 8 + wm * 4;
    #pragma unroll
    for (int tm = 0; tm < 4; ++tm)
      #pragma unroll
      for (int kk = 0; kk < 4; ++kk)
        af[tm][kk] = wp[(s0 + tm) * 256 + kk * 64 + l];
  }

  float psum[2] = {0.f, 0.f};

  for (int ct = slice; ct < NMT; ct += SLICES) {
    const int ct0 = ct * 128;
    const int nct = ct + SLICES;
    const bool hasnext = (nct < NMT);
    const int ns0 = nct * 8 + wm * 4;

    facc4 bias4[4]; int cvalid[4];
    #pragma unroll
    for (int tm = 0; tm < 4; ++tm) {
      int cb = ct0 + wm * 64 + tm * 16 + quad * 4;
      cvalid[tm] = (cb < NC);
      facc4 bv = cvalid[tm] ? *(const facc4*)(bias + cb)
                            : (facc4){0.f, 0.f, 0.f, 0.f};
      bias4[tm] = bv * LOG2E;
    }

    facc4 acc[4][2];
    #pragma unroll
    for (int a = 0; a < 4; ++a)
      #pragma unroll
      for (int b = 0; b < 2; ++b) acc[a][b] = (facc4){0.f, 0.f, 0.f, 0.f};

    // kk-granular software pipeline: consume af[*][kk], then refill it
    // with the NEXT tile's slab (WAR keeps order; ~full iteration of
    // latency cover before next use).
    #pragma unroll
    for (int kk = 0; kk < 4; ++kk) {
      #pragma unroll
      for (int tm = 0; tm < 4; ++tm)
        #pragma unroll
        for (int tn = 0; tn < 2; ++tn)
          acc[tm][tn] = __builtin_amdgcn_mfma_f32_16x16x32_bf16(
              af[tm][kk], xf[tn][kk], acc[tm][tn], 0, 0, 0);
      if (hasnext) {
        #pragma unroll
        for (int tm = 0; tm < 4; ++tm)
          af[tm][kk] = wp[(ns0 + tm) * 256 + kk * 64 + l];
      }
    }

    // ---- epilogue: native exp2/log2 (log2e folded into Wt/bias) ----------
    if (STATS) {
      #pragma unroll
      for (int tn = 0; tn < 2; ++tn) {
        float p = 0.f;
        #pragma unroll
        for (int tm = 0; tm < 4; ++tm) {
          if (cvalid[tm]) {
            #pragma unroll
            for (int rg = 0; rg < 4; ++rg)
              p += exp2f(acc[tm][tn][rg] + bias4[tm][rg]);
          }
        }
        psum[tn] += p;
      }
    } else {
      // per row each wave writes its full 64-class span = 256B = two full
      // 128B lines within one burst -> L2 write-combines (round-3
      // WRITE_SIZE == ideal confirmed this works).
      #pragma unroll
      for (int tn = 0; tn < 2; ++tn) {
        int b = wn * 32 + tn * 16 + lane15;
        float* orow = out + (size_t)(bt0 + b) * NC;
        #pragma unroll
        for (int tm = 0; tm < 4; ++tm) {
          if (cvalid[tm]) {
            int cb = ct0 + wm * 64 + tm * 16 + quad * 4;
            facc4 o;
            #pragma unroll
            for (int rg = 0; rg < 4; ++rg) {
              float e = exp2f(acc[tm][tn][rg] + bias4[tm][rg]);
              o[rg] = NLN2 * log2f(Sv[tn] - e);
            }
            *(facc4*)(orow + cb) = o;
          }
        }
      }
    }
  }

  if (STATS) {
    #pragma unroll
    for (int tn = 0; tn < 2; ++tn) {
      float p = psum[tn];
      p += __shfl_xor(p, 16, 64);
      p += __shfl_xor(p, 32, 64);
      if (quad == 0)
        atomicAdd(&S[bt0 + wn * 32 + tn * 16 + lane15], p);
    }
  }
}

extern "C" void kernel_launch(void* const* d_in, const int* in_sizes, int n_in,
                              void* d_out, int out_size, void* d_ws, size_t ws_size,
                              hipStream_t stream) {
  const float* x    = (const float*)d_in[0];   // [8192][128]
  const float* W    = (const float*)d_in[1];   // [128][10000]
  const float* bias = (const float*)d_in[2];   // [10000]
  float* out = (float*)d_out;

  char* ws = (char*)d_ws;
  unsigned short* xb = (unsigned short*)ws;                          // 2 MB
  unsigned short* Wt = (unsigned short*)(ws + (size_t)NB * ND * 2);  // 2.59 MB
  float* S = (float*)(ws + (size_t)NB * ND * 2 + (size_t)NCPAD * ND * 2);

  prep_kernel<<<TOTJOBS, 256, 0, stream>>>(x, W, xb, Wt, S);
  gemm_pass<1><<<GRID, 256, 0, stream>>>(xb, Wt, bias, S, nullptr);
  gemm_pass<0><<<GRID, 256, 0, stream>>>(xb, Wt, bias, S, out);
}

// Round 6
// 417.816 us; speedup vs baseline: 1.0089x; 1.0089x over previous
//
#include <hip/hip_runtime.h>
#include <hip/hip_bf16.h>

#define NB 8192
#define ND 128
#define NC 10000
#define NMT 79                 // class tiles (128 wide), ceil(10000/128)
#define NCPAD (NMT * 128)      // 10112
#define BT 64                  // batch rows per GEMM block

// out pass (LDS/barrier, R4 structure)
#define SLICES_OUT 6
#define GRID_OUT ((NB / BT) * SLICES_OUT)   // 768 = 3 blocks/CU
// stats pass (register-streamed, R5 structure)
#define SLICES_ST 4
#define GRID_ST ((NB / BT) * SLICES_ST)     // 512 = 2 blocks/CU

#define LOG2E 1.4426950408889634f
#define NLN2  (-0.6931471805599453f)

typedef short bfrag8 __attribute__((ext_vector_type(8)));  // 8 bf16 (4 VGPRs)
typedef float facc4 __attribute__((ext_vector_type(4)));   // MFMA C/D

__device__ __forceinline__ unsigned short f2bf(float f) {
  union { float f; unsigned u; } v; v.f = f;
  unsigned r = v.u + 0x7FFFu + ((v.u >> 16) & 1u);  // RNE
  return (unsigned short)(r >> 16);
}

// ===== prep: writes BOTH layouts =========================================
// Row-major xb_row[b][d] / Wt_row[c][d] feed the out pass (global_load_lds
// staging). Fragment-order xb_fr / Wt_fr feed the barrier-free stats pass:
//   unit16B(strip s, kk, quad, l15) at index s*256 + kk*64 + quad*16 + l15
// holds row s*16+l15, d [kk*32+quad*8 .. +8) -- one coalesced 1KB
// global_load_dwordx4 per MFMA fragment. W and bias are pre-scaled by
// log2e so both GEMM epilogues use native exp2/log2; both passes see
// bitwise-identical logits -> the exp term in -log(S - e) cancels exactly.
#define XRJOBS 1024            // row-major x: 262144 float4 / 256 threads
#define XFJOBS 512             // frag-order x: one 16-row strip per block
#define SJOBS 32               // S zero: 8192 / 256
#define WJOBS (316 * 4)        // 32x32 transpose tiles (writes both layouts)
#define TOTJOBS (XRJOBS + XFJOBS + SJOBS + WJOBS)

__global__ void prep_kernel(const float* __restrict__ x,
                            const float* __restrict__ W,
                            unsigned short* __restrict__ xb_row,
                            unsigned short* __restrict__ xb_fr,
                            unsigned short* __restrict__ Wt_row,
                            unsigned short* __restrict__ Wt_fr,
                            float* __restrict__ S) {
  int job = blockIdx.x, tid = threadIdx.x;
  if (job < XRJOBS) {
    int i = job * 256 + tid;                 // 4 floats / thread
    float4 v = ((const float4*)x)[i];
    ushort4 o;
    o.x = f2bf(v.x); o.y = f2bf(v.y); o.z = f2bf(v.z); o.w = f2bf(v.w);
    ((ushort4*)xb_row)[i] = o;
  } else if (job < XRJOBS + XFJOBS) {
    int jb = job - XRJOBS;
    int kk = tid >> 6, quad = (tid >> 4) & 3, l15 = tid & 15;
    int row = jb * 16 + l15, chunk = kk * 4 + quad;
    const float4* xr = (const float4*)(x + (size_t)row * ND + chunk * 8);
    float4 a = xr[0], b = xr[1];
    ushort4 o0, o1;
    o0.x = f2bf(a.x); o0.y = f2bf(a.y); o0.z = f2bf(a.z); o0.w = f2bf(a.w);
    o1.x = f2bf(b.x); o1.y = f2bf(b.y); o1.z = f2bf(b.z); o1.w = f2bf(b.w);
    ushort4* op = (ushort4*)(xb_fr + ((size_t)jb * 256 + tid) * 8);
    op[0] = o0; op[1] = o1;
  } else if (job < XRJOBS + XFJOBS + SJOBS) {
    S[(job - XRJOBS - XFJOBS) * 256 + tid] = 0.f;  // ws re-poisoned 0xAA
  } else {
    __shared__ float t[32][33];              // t[d_local][c_local]
    int j = job - XRJOBS - XFJOBS - SJOBS;
    int c0 = (j >> 2) * 32, r0 = (j & 3) * 32;   // classes c0.., d r0..
    int tx = tid & 31, ty = tid >> 5;        // (32, 8)
    #pragma unroll
    for (int i = 0; i < 4; ++i) {
      int r = r0 + ty + i * 8, c = c0 + tx;  // r < 128 always
      t[ty + i * 8][tx] = (c < NC) ? W[(size_t)r * NC + c] : 0.f;
    }
    __syncthreads();
    // row-major store (out pass input)
    #pragma unroll
    for (int i = 0; i < 4; ++i) {
      int c = c0 + ty + i * 8, r = r0 + tx;  // c < NCPAD
      Wt_row[(size_t)c * ND + r] = f2bf(t[tx][ty + i * 8] * LOG2E);
    }
    // frag-order store (stats pass input)
    if (tid < 128) {
      int c_local = tid >> 2, ch = tid & 3;
      int c = c0 + c_local;
      int s = c >> 4, l15 = c & 15;
      int kk = r0 >> 5, quad = ch;           // chunk = r0/8 + ch = kk*4+quad
      ushort4 o0, o1;
      o0.x = f2bf(t[ch * 8 + 0][c_local] * LOG2E);
      o0.y = f2bf(t[ch * 8 + 1][c_local] * LOG2E);
      o0.z = f2bf(t[ch * 8 + 2][c_local] * LOG2E);
      o0.w = f2bf(t[ch * 8 + 3][c_local] * LOG2E);
      o1.x = f2bf(t[ch * 8 + 4][c_local] * LOG2E);
      o1.y = f2bf(t[ch * 8 + 5][c_local] * LOG2E);
      o1.z = f2bf(t[ch * 8 + 6][c_local] * LOG2E);
      o1.w = f2bf(t[ch * 8 + 7][c_local] * LOG2E);
      ushort4* op = (ushort4*)(Wt_fr +
          ((size_t)s * 256 + kk * 64 + quad * 16 + l15) * 8);
      op[0] = o0; op[1] = o1;
    }
  }
}

// ===== stats pass: zero LDS, zero barriers, register-streamed ============
// No stores -> no store/vmcnt coupling; each wave fully independent. X
// operand (32 rows x 128 d) resident in 32 VGPRs; W fragments stream
// through a 64-VGPR buffer, refilled per-kk right after consumption.
__global__ __launch_bounds__(256, 2) void stats_pass(
    const unsigned short* __restrict__ xb_fr,  // frag-order bf16
    const unsigned short* __restrict__ Wt_fr,  // frag-order bf16 (x log2e)
    const float* __restrict__ bias,            // [NC]
    float* __restrict__ S) {                   // [NB]
  const int bid = blockIdx.x;
  const int slice = bid % SLICES_ST, bt0 = (bid / SLICES_ST) * BT;
  const int tid = threadIdx.x;
  const int w = tid >> 6, l = tid & 63;
  const int lane15 = l & 15, quad = l >> 4;
  const int wm = w >> 1, wn = w & 1;

  const bfrag8* xp = (const bfrag8*)xb_fr;
  const bfrag8* wp = (const bfrag8*)Wt_fr;

  bfrag8 xf[2][4];
  #pragma unroll
  for (int tn = 0; tn < 2; ++tn) {
    int sx = (bt0 >> 4) + wn * 2 + tn;
    #pragma unroll
    for (int kk = 0; kk < 4; ++kk)
      xf[tn][kk] = xp[sx * 256 + kk * 64 + l];
  }

  bfrag8 af[4][4];
  {
    int s0 = slice * 8 + wm * 4;
    #pragma unroll
    for (int tm = 0; tm < 4; ++tm)
      #pragma unroll
      for (int kk = 0; kk < 4; ++kk)
        af[tm][kk] = wp[(s0 + tm) * 256 + kk * 64 + l];
  }

  float psum[2] = {0.f, 0.f};

  for (int ct = slice; ct < NMT; ct += SLICES_ST) {
    const int ct0 = ct * 128;
    const int nct = ct + SLICES_ST;
    const bool hasnext = (nct < NMT);
    const int ns0 = nct * 8 + wm * 4;

    facc4 bias4[4]; int cvalid[4];
    #pragma unroll
    for (int tm = 0; tm < 4; ++tm) {
      int cb = ct0 + wm * 64 + tm * 16 + quad * 4;
      cvalid[tm] = (cb < NC);
      facc4 bv = cvalid[tm] ? *(const facc4*)(bias + cb)
                            : (facc4){0.f, 0.f, 0.f, 0.f};
      bias4[tm] = bv * LOG2E;
    }

    facc4 acc[4][2];
    #pragma unroll
    for (int a = 0; a < 4; ++a)
      #pragma unroll
      for (int b = 0; b < 2; ++b) acc[a][b] = (facc4){0.f, 0.f, 0.f, 0.f};

    #pragma unroll
    for (int kk = 0; kk < 4; ++kk) {
      #pragma unroll
      for (int tm = 0; tm < 4; ++tm)
        #pragma unroll
        for (int tn = 0; tn < 2; ++tn)
          acc[tm][tn] = __builtin_amdgcn_mfma_f32_16x16x32_bf16(
              af[tm][kk], xf[tn][kk], acc[tm][tn], 0, 0, 0);
      if (hasnext) {
        #pragma unroll
        for (int tm = 0; tm < 4; ++tm)
          af[tm][kk] = wp[(ns0 + tm) * 256 + kk * 64 + l];
      }
    }

    #pragma unroll
    for (int tn = 0; tn < 2; ++tn) {
      float p = 0.f;
      #pragma unroll
      for (int tm = 0; tm < 4; ++tm) {
        if (cvalid[tm]) {
          #pragma unroll
          for (int rg = 0; rg < 4; ++rg)
            p += exp2f(acc[tm][tn][rg] + bias4[tm][rg]);
        }
      }
      psum[tn] += p;
    }
  }

  #pragma unroll
  for (int tn = 0; tn < 2; ++tn) {
    float p = psum[tn];
    p += __shfl_xor(p, 16, 64);
    p += __shfl_xor(p, 32, 64);
    if (quad == 0)
      atomicAdd(&S[bt0 + wn * 32 + tn * 16 + lane15], p);
  }
}

// ===== out pass: R4's LDS/barrier kernel verbatim (proven store path) ====
__global__ __launch_bounds__(256, 3) void out_pass(
    const unsigned short* __restrict__ xb,   // [NB][128] bf16 row-major
    const unsigned short* __restrict__ Wt,   // [NCPAD][128] bf16 (x log2e)
    const float* __restrict__ bias,          // [NC]
    const float* __restrict__ S,             // [NB]
    float* __restrict__ out) {               // [NB][NC]
  __shared__ __align__(16) unsigned short Xl[BT * 128];   // 16 KB
  __shared__ __align__(16) unsigned short Wl[128 * 128];  // 32 KB
  __shared__ float sS[BT];

  const int bid = blockIdx.x;
  const int slice = bid % SLICES_OUT, bt0 = (bid / SLICES_OUT) * BT;
  const int tid = threadIdx.x;
  const int w = tid >> 6, l = tid & 63;
  const int lane15 = l & 15, quad = l >> 4;
  const int wm = w >> 1, wn = w & 1;

  #pragma unroll
  for (int i = 0; i < 4; ++i) {
    int bbase = i * 256 + w * 64;
    int bi = bbase + l;
    int r = bi >> 4, j = bi & 15;
    int jg = j ^ (r & 15);
    __builtin_amdgcn_global_load_lds(
        (const unsigned int*)(xb + (size_t)(bt0 + r) * ND + jg * 8),
        (unsigned int*)(Xl + bbase * 8), 16, 0, 0);
  }
  #pragma unroll
  for (int i = 0; i < 8; ++i) {
    int bbase = i * 256 + w * 64;
    int bi = bbase + l;
    int r = bi >> 4, j = bi & 15;
    int jg = j ^ (r & 15);
    __builtin_amdgcn_global_load_lds(
        (const unsigned int*)(Wt + (size_t)(slice * 128 + r) * ND + jg * 8),
        (unsigned int*)(Wl + bbase * 8), 16, 0, 0);
  }
  if (tid < BT) sS[tid] = S[bt0 + tid];

  int first = 1;

  for (int ct = slice; ct < NMT; ct += SLICES_OUT) {
    const int ct0 = ct * 128;
    facc4 bias4[4]; int cvalid[4];
    #pragma unroll
    for (int tm = 0; tm < 4; ++tm) {
      int cb = ct0 + wm * 64 + tm * 16 + quad * 4;
      cvalid[tm] = (cb < NC);
      facc4 bv = cvalid[tm] ? *(const facc4*)(bias + cb)
                            : (facc4){0.f, 0.f, 0.f, 0.f};
      bias4[tm] = bv * LOG2E;
    }

    if (first) {
      __syncthreads();                       // full drain incl. sS publish
      first = 0;
    } else {
      // own 8 W-prefetch gl_lds landed; <=8 prior stores stay in flight
      asm volatile("s_waitcnt vmcnt(8)" ::: "memory");
      __builtin_amdgcn_sched_barrier(0);
      __builtin_amdgcn_s_barrier();
      __builtin_amdgcn_sched_barrier(0);
    }

    facc4 acc[4][2];
    #pragma unroll
    for (int a = 0; a < 4; ++a)
      #pragma unroll
      for (int b = 0; b < 2; ++b) acc[a][b] = (facc4){0.f, 0.f, 0.f, 0.f};

    #pragma unroll
    for (int kk = 0; kk < 4; ++kk) {
      bfrag8 af[4], bf[2];
      const int jj = (kk * 4 + quad) ^ lane15;
      #pragma unroll
      for (int tm = 0; tm < 4; ++tm)
        af[tm] = *(const bfrag8*)(Wl + (wm * 64 + tm * 16 + lane15) * 128 + jj * 8);
      #pragma unroll
      for (int tn = 0; tn < 2; ++tn)
        bf[tn] = *(const bfrag8*)(Xl + (wn * 32 + tn * 16 + lane15) * 128 + jj * 8);
      #pragma unroll
      for (int tm = 0; tm < 4; ++tm)
        #pragma unroll
        for (int tn = 0; tn < 2; ++tn)
          acc[tm][tn] = __builtin_amdgcn_mfma_f32_16x16x32_bf16(
              af[tm], bf[tn], acc[tm][tn], 0, 0, 0);
    }

    __builtin_amdgcn_sched_barrier(0);
    __builtin_amdgcn_s_barrier();
    __builtin_amdgcn_sched_barrier(0);

    if (ct + SLICES_OUT < NMT) {
      const int nct0 = (ct + SLICES_OUT) * 128;
      #pragma unroll
      for (int i = 0; i < 8; ++i) {
        int bbase = i * 256 + w * 64;
        int bi = bbase + l;
        int r = bi >> 4, j = bi & 15;
        int jg = j ^ (r & 15);
        __builtin_amdgcn_global_load_lds(
            (const unsigned int*)(Wt + (size_t)(nct0 + r) * ND + jg * 8),
            (unsigned int*)(Wl + bbase * 8), 16, 0, 0);
      }
    }

    #pragma unroll
    for (int tn = 0; tn < 2; ++tn) {
      int b = wn * 32 + tn * 16 + lane15;
      float Sv = sS[b];
      float* orow = out + (size_t)(bt0 + b) * NC;
      #pragma unroll
      for (int tm = 0; tm < 4; ++tm) {
        if (cvalid[tm]) {
          int cb = ct0 + wm * 64 + tm * 16 + quad * 4;
          facc4 o;
          #pragma unroll
          for (int rg = 0; rg < 4; ++rg) {
            float e = exp2f(acc[tm][tn][rg] + bias4[tm][rg]);
            o[rg] = NLN2 * log2f(Sv - e);
          }
          *(facc4*)(orow + cb) = o;
        }
      }
    }
  }
}

extern "C" void kernel_launch(void* const* d_in, const int* in_sizes, int n_in,
                              void* d_out, int out_size, void* d_ws, size_t ws_size,
                              hipStream_t stream) {
  const float* x    = (const float*)d_in[0];   // [8192][128]
  const float* W    = (const float*)d_in[1];   // [128][10000]
  const float* bias = (const float*)d_in[2];   // [10000]
  float* out = (float*)d_out;

  char* ws = (char*)d_ws;
  const size_t XBN = (size_t)NB * ND * 2;      // 2 MB
  const size_t WTN = (size_t)NCPAD * ND * 2;   // 2.59 MB
  unsigned short* xb_row = (unsigned short*)ws;
  unsigned short* xb_fr  = (unsigned short*)(ws + XBN);
  unsigned short* Wt_row = (unsigned short*)(ws + 2 * XBN);
  unsigned short* Wt_fr  = (unsigned short*)(ws + 2 * XBN + WTN);
  float* S = (float*)(ws + 2 * XBN + 2 * WTN);

  prep_kernel<<<TOTJOBS, 256, 0, stream>>>(x, W, xb_row, xb_fr, Wt_row,
                                           Wt_fr, S);
  stats_pass<<<GRID_ST, 256, 0, stream>>>(xb_fr, Wt_fr, bias, S);
  out_pass<<<GRID_OUT, 256, 0, stream>>>(xb_row, Wt_row, bias, S, out);
}

// Round 7
// 416.813 us; speedup vs baseline: 1.0113x; 1.0024x over previous
//
#include <hip/hip_runtime.h>
#include <hip/hip_bf16.h>

#define NB 8192
#define ND 128
#define NC 10000
#define NMT 79                 // class tiles (128 wide), ceil(10000/128)
#define NCPAD (NMT * 128)      // 10112
#define BT 64                  // batch rows per GEMM block
#define SLICES 4               // class-tile slices per batch-tile
#define GRID ((NB / BT) * SLICES)  // 512 blocks = exactly 2/CU

#define LOG2E 1.4426950408889634f
#define NLN2  (-0.6931471805599453f)

typedef short bfrag8 __attribute__((ext_vector_type(8)));  // 8 bf16 (4 VGPRs)
typedef float facc4 __attribute__((ext_vector_type(4)));   // MFMA C/D

__device__ __forceinline__ unsigned short f2bf(float f) {
  union { float f; unsigned u; } v; v.f = f;
  unsigned r = v.u + 0x7FFFu + ((v.u >> 16) & 1u);  // RNE
  return (unsigned short)(r >> 16);
}

// ===== prep: frag-order x | S=0 | row-major W^T (x log2e) ================
// xb_fr unit16B(strip s, kk, quad, l15) at index s*256+kk*64+quad*16+l15
// holds row s*16+l15, d [kk*32+quad*8 .. +8) -- the exact
// mfma_f32_16x16x32_bf16 B-fragment, loaded once into registers by both
// GEMM passes. Wt row-major [NCPAD][128] feeds global_load_lds staging.
// W/bias pre-scaled by log2e -> native exp2/log2 in epilogues; both passes
// compute bitwise-identical logits -> exp term in -log(S-e) cancels exactly.
#define XFJOBS 512             // one 16-row strip (256 16B units) per block
#define SJOBS 32               // 8192 / 256
#define WJOBS (316 * 4)        // (NCPAD/32) x (128/32) 32x32 transpose tiles
#define TOTJOBS (XFJOBS + SJOBS + WJOBS)

__global__ void prep_kernel(const float* __restrict__ x,
                            const float* __restrict__ W,
                            unsigned short* __restrict__ xb_fr,
                            unsigned short* __restrict__ Wt,
                            float* __restrict__ S) {
  int job = blockIdx.x, tid = threadIdx.x;
  if (job < XFJOBS) {
    int kk = tid >> 6, quad = (tid >> 4) & 3, l15 = tid & 15;
    int row = job * 16 + l15, chunk = kk * 4 + quad;
    const float4* xr = (const float4*)(x + (size_t)row * ND + chunk * 8);
    float4 a = xr[0], b = xr[1];
    ushort4 o0, o1;
    o0.x = f2bf(a.x); o0.y = f2bf(a.y); o0.z = f2bf(a.z); o0.w = f2bf(a.w);
    o1.x = f2bf(b.x); o1.y = f2bf(b.y); o1.z = f2bf(b.z); o1.w = f2bf(b.w);
    ushort4* op = (ushort4*)(xb_fr + ((size_t)job * 256 + tid) * 8);
    op[0] = o0; op[1] = o1;
  } else if (job < XFJOBS + SJOBS) {
    S[(job - XFJOBS) * 256 + tid] = 0.f;     // ws re-poisoned 0xAA
  } else {
    __shared__ float t[32][33];              // t[d_local][c_local]
    int j = job - XFJOBS - SJOBS;
    int c0 = (j >> 2) * 32, r0 = (j & 3) * 32;   // classes c0.., d r0..
    int tx = tid & 31, ty = tid >> 5;        // (32, 8)
    #pragma unroll
    for (int i = 0; i < 4; ++i) {
      int r = r0 + ty + i * 8, c = c0 + tx;  // r < 128 always
      t[ty + i * 8][tx] = (c < NC) ? W[(size_t)r * NC + c] : 0.f;
    }
    __syncthreads();
    #pragma unroll
    for (int i = 0; i < 4; ++i) {
      int c = c0 + ty + i * 8, r = r0 + tx;  // c < NCPAD
      Wt[(size_t)c * ND + r] = f2bf(t[tx][ty + i * 8] * LOG2E);
    }
  }
}

// ---- W tile staging: 8 x global_load_lds dwordx4 per wave (32KB/block) --
// XOR swizzle j ^= (r & 15) pre-applied on the GLOBAL source address so the
// LDS image is the swizzled layout the fragment reads expect (R4-proven,
// SQ_LDS_BANK_CONFLICT == 0 in the R3 fused profile).
__device__ __forceinline__ void stage_w(const unsigned short* __restrict__ Wt,
                                        unsigned short* dst, int row0,
                                        int w, int l) {
  #pragma unroll
  for (int i = 0; i < 8; ++i) {
    int bbase = i * 256 + w * 64;            // wave-uniform 16B-block base
    int bi = bbase + l;
    int r = bi >> 4, j = bi & 15;
    int jg = j ^ (r & 15);
    __builtin_amdgcn_global_load_lds(
        (const unsigned int*)(Wt + (size_t)(row0 + r) * ND + jg * 8),
        (unsigned int*)(dst + bbase * 8), 16, 0, 0);
  }
}

// ===== GEMM pass: single-barrier double-buffered pipeline ================
// R4 had 2 barriers/tile and epilogue-only prefetch cover; R3 counters
// showed pure serialization (MfmaUtil 6.7 / VALU 23 / HBM 17, none
// saturated). New per-tile schedule:
//   vmcnt(own tile-t loads landed) -> s_barrier  [all waves' loads landed;
//   all waves' prev-tile LDS reads lgkm-drained pre-barrier]
//   -> issue tile t+1 into buf^1   [full-iteration latency cover]
//   -> MFMA from buf -> epilogue.
// vmcnt by in-order retirement: stats vmcnt(0) (only tile t in flight at
// that point -- t+1 not yet issued); out vmcnt(8) (prev tile's 8 stores
// stay in flight; the only partial-store tile is the global last, which
// has no subsequent wait). X operand lives in registers (loaded once from
// frag-order xb, R5-proven); no Xl, no sS -> LDS 64.25KB -> 2 blocks/CU.
template <int STATS>
__global__ __launch_bounds__(256, 2) void gemm_pass(
    const unsigned short* __restrict__ xb_fr,  // frag-order bf16
    const unsigned short* __restrict__ Wt,     // [NCPAD][128] bf16 (x log2e)
    const float* __restrict__ bias,            // [NC]
    float* __restrict__ S,                     // [NB]
    float* __restrict__ out) {                 // [NB][NC]
  __shared__ __align__(16) unsigned short Wl[2][128 * 128];  // 2 x 32 KB

  const int bid = blockIdx.x;
  const int slice = bid % SLICES, bt0 = (bid / SLICES) * BT;
  const int tid = threadIdx.x;
  const int w = tid >> 6, l = tid & 63;
  const int lane15 = l & 15, quad = l >> 4;
  const int wm = w >> 1, wn = w & 1;         // wm: class half, wn: batch half

  // ---- X operand: resident in registers for the whole kernel ------------
  const bfrag8* xp = (const bfrag8*)xb_fr;
  bfrag8 xf[2][4];
  #pragma unroll
  for (int tn = 0; tn < 2; ++tn) {
    int sx = (bt0 >> 4) + wn * 2 + tn;
    #pragma unroll
    for (int kk = 0; kk < 4; ++kk)
      xf[tn][kk] = xp[sx * 256 + kk * 64 + l];
  }
  float Sv[2];
  if (!STATS) {
    #pragma unroll
    for (int tn = 0; tn < 2; ++tn)
      Sv[tn] = S[bt0 + wn * 32 + tn * 16 + lane15];
  }

  const int ntiles = (NMT - slice + SLICES - 1) / SLICES;

  // ---- prologue: issue tile 0 -> buf 0 -----------------------------------
  stage_w(Wt, Wl[0], slice * 128, w, l);

  float psum[2] = {0.f, 0.f};

  for (int it = 0; it < ntiles; ++it) {
    const int ct = slice + it * SLICES;
    const int ct0 = ct * 128;
    const int cur = it & 1;
    unsigned short* WlC = Wl[cur];

    // own tile-it loads landed (in-order vmcnt); barrier -> ALL waves'
    // loads landed AND all prev-tile LDS reads complete (their data was
    // consumed by pre-barrier MFMAs -> lgkm drained) -> buf^1 overwritable.
    if (STATS || it == 0) {
      asm volatile("s_waitcnt vmcnt(0)" ::: "memory");
    } else {
      asm volatile("s_waitcnt vmcnt(8)" ::: "memory");
    }
    __builtin_amdgcn_sched_barrier(0);
    __builtin_amdgcn_s_barrier();
    __builtin_amdgcn_sched_barrier(0);

    // ---- issue tile it+1: flies under this whole iteration ---------------
    if (it + 1 < ntiles)
      stage_w(Wt, Wl[cur ^ 1], (ct + SLICES) * 128, w, l);
    __builtin_amdgcn_sched_barrier(0);

    // bias (x log2e) for this tile's 4 class quads; NC%16==0 so 16-class
    // tiles are entirely valid or entirely invalid.
    facc4 bias4[4]; int cvalid[4];
    #pragma unroll
    for (int tm = 0; tm < 4; ++tm) {
      int cb = ct0 + wm * 64 + tm * 16 + quad * 4;
      cvalid[tm] = (cb < NC);
      facc4 bv = cvalid[tm] ? *(const facc4*)(bias + cb)
                            : (facc4){0.f, 0.f, 0.f, 0.f};
      bias4[tm] = bv * LOG2E;
    }

    // ---- MFMA: 4 K-steps of 32; wave (wm,wn) owns 64x32 = 4x2 tiles ------
    facc4 acc[4][2];
    #pragma unroll
    for (int a = 0; a < 4; ++a)
      #pragma unroll
      for (int b = 0; b < 2; ++b) acc[a][b] = (facc4){0.f, 0.f, 0.f, 0.f};

    #pragma unroll
    for (int kk = 0; kk < 4; ++kk) {
      bfrag8 af[4];
      const int jj = (kk * 4 + quad) ^ lane15;  // swizzled 16B-block in row
      #pragma unroll
      for (int tm = 0; tm < 4; ++tm)
        af[tm] = *(const bfrag8*)(WlC + (wm * 64 + tm * 16 + lane15) * 128 + jj * 8);
      #pragma unroll
      for (int tm = 0; tm < 4; ++tm)
        #pragma unroll
        for (int tn = 0; tn < 2; ++tn)
          acc[tm][tn] = __builtin_amdgcn_mfma_f32_16x16x32_bf16(
              af[tm], xf[tn][kk], acc[tm][tn], 0, 0, 0);
    }

    // ---- epilogue: native exp2/log2 (log2e folded into Wt/bias) ----------
    if (STATS) {
      #pragma unroll
      for (int tn = 0; tn < 2; ++tn) {
        float p = 0.f;
        #pragma unroll
        for (int tm = 0; tm < 4; ++tm) {
          if (cvalid[tm]) {
            #pragma unroll
            for (int rg = 0; rg < 4; ++rg)
              p += exp2f(acc[tm][tn][rg] + bias4[tm][rg]);
          }
        }
        psum[tn] += p;
      }
    } else {
      // tn outer / tm inner: 4 stores per row cover 256B contiguous ->
      // two full 128B lines -> L2 write-combines (WRITE_SIZE == ideal,
      // confirmed in the R3 fused profile).
      #pragma unroll
      for (int tn = 0; tn < 2; ++tn) {
        int b = wn * 32 + tn * 16 + lane15;
        float* orow = out + (size_t)(bt0 + b) * NC;
        #pragma unroll
        for (int tm = 0; tm < 4; ++tm) {
          if (cvalid[tm]) {
            int cb = ct0 + wm * 64 + tm * 16 + quad * 4;
            facc4 o;
            #pragma unroll
            for (int rg = 0; rg < 4; ++rg) {
              float e = exp2f(acc[tm][tn][rg] + bias4[tm][rg]);
              o[rg] = NLN2 * log2f(Sv[tn] - e);
            }
            *(facc4*)(orow + cb) = o;
          }
        }
      }
    }
  }

  if (STATS) {
    #pragma unroll
    for (int tn = 0; tn < 2; ++tn) {
      float p = psum[tn];
      p += __shfl_xor(p, 16, 64);
      p += __shfl_xor(p, 32, 64);
      if (quad == 0)
        atomicAdd(&S[bt0 + wn * 32 + tn * 16 + lane15], p);
    }
  }
}

extern "C" void kernel_launch(void* const* d_in, const int* in_sizes, int n_in,
                              void* d_out, int out_size, void* d_ws, size_t ws_size,
                              hipStream_t stream) {
  const float* x    = (const float*)d_in[0];   // [8192][128]
  const float* W    = (const float*)d_in[1];   // [128][10000]
  const float* bias = (const float*)d_in[2];   // [10000]
  float* out = (float*)d_out;

  char* ws = (char*)d_ws;
  const size_t XBN = (size_t)NB * ND * 2;      // 2 MB
  const size_t WTN = (size_t)NCPAD * ND * 2;   // 2.59 MB
  unsigned short* xb_fr = (unsigned short*)ws;
  unsigned short* Wt    = (unsigned short*)(ws + XBN);
  float* S = (float*)(ws + XBN + WTN);

  prep_kernel<<<TOTJOBS, 256, 0, stream>>>(x, W, xb_fr, Wt, S);
  gemm_pass<1><<<GRID, 256, 0, stream>>>(xb_fr, Wt, bias, S, nullptr);
  gemm_pass<0><<<GRID, 256, 0, stream>>>(xb_fr, Wt, bias, S, out);
}

// Round 8
// 400.481 us; speedup vs baseline: 1.0525x; 1.0408x over previous
//
#include <hip/hip_runtime.h>
#include <hip/hip_bf16.h>

#define NB 8192
#define ND 128
#define NC 10000
#define NMT 79                 // class tiles (128 wide), ceil(10000/128)
#define NCPAD (NMT * 128)      // 10112
#define BT 64                  // batch rows per GEMM block
#define NBT (NB / BT)          // 128 batch tiles
#define SLICES 6               // class-tile slices per batch-tile
#define GRID (NBT * SLICES)    // 768 blocks = exactly 3/CU on 256 CUs

#define LOG2E 1.4426950408889634f
#define NLN2  (-0.6931471805599453f)

typedef short bfrag8 __attribute__((ext_vector_type(8)));  // 8 bf16 (4 VGPRs)
typedef float facc4 __attribute__((ext_vector_type(4)));   // MFMA C/D

__device__ __forceinline__ unsigned short f2bf(float f) {
  union { float f; unsigned u; } v; v.f = f;
  unsigned r = v.u + 0x7FFFu + ((v.u >> 16) & 1u);  // RNE
  return (unsigned short)(r >> 16);
}

// ---- fused prep: x->bf16 | S=0 | W transpose+convert, by block range ----
// W is pre-scaled by log2e so the GEMM epilogues use native v_exp_f32 /
// v_log_f32 (exp2/log2) with no per-value range-conversion mul. Both GEMM
// passes see the same scaled Wt -> logits bitwise identical -> the exp
// cancellation in -log(S - e) stays exact.
#define XJOBS 1024             // 262144 float4 / 256 threads
#define SJOBS 32               // 8192 / 256
#define WJOBS (316 * 4)        // (NCPAD/32) x (128/32) 32x32 transpose tiles

__global__ void prep_kernel(const float* __restrict__ x,
                            const float* __restrict__ W,
                            unsigned short* __restrict__ xb,
                            unsigned short* __restrict__ Wt,
                            float* __restrict__ S) {
  int job = blockIdx.x, tid = threadIdx.x;
  if (job < XJOBS) {
    int i = job * 256 + tid;                 // 4 floats / thread
    float4 v = ((const float4*)x)[i];
    ushort4 o;
    o.x = f2bf(v.x); o.y = f2bf(v.y); o.z = f2bf(v.z); o.w = f2bf(v.w);
    ((ushort4*)xb)[i] = o;
  } else if (job < XJOBS + SJOBS) {
    S[(job - XJOBS) * 256 + tid] = 0.f;      // ws is re-poisoned 0xAA
  } else {
    __shared__ float t[32][33];
    int j = job - XJOBS - SJOBS;
    int c0 = (j >> 2) * 32, r0 = (j & 3) * 32;
    int tx = tid & 31, ty = tid >> 5;        // (32, 8)
    #pragma unroll
    for (int i = 0; i < 4; ++i) {
      int r = r0 + ty + i * 8, c = c0 + tx;  // r < 128 always
      t[ty + i * 8][tx] = (c < NC) ? W[(size_t)r * NC + c] : 0.f;
    }
    __syncthreads();
    #pragma unroll
    for (int i = 0; i < 4; ++i) {
      int c = c0 + ty + i * 8, r = r0 + tx;  // c < NCPAD
      Wt[(size_t)c * ND + r] = f2bf(t[tx][ty + i * 8] * LOG2E);
    }
  }
}

// ---- GEMM pass: block = (batch-tile 64, slice); jobs = class tiles ------
// 48KB LDS (Xl 16K + Wl 32K) -> 3 blocks/CU. R3 fused counters showed
// latency-bound (MfmaUtil 6.7%, VALU 23%, HBM 17%, occ 22%); R5/R6/R7
// structural alternatives (reg-streamed W, hybrid, single-barrier dbuf)
// all regressed -- this 2-barrier global_load_lds structure is the
// empirical optimum for this tiny-K GEMM. Wave (wm,wn) owns 64 classes x
// 32 batch (acc[4][2]). Wl software-pipelined with raw s_barrier + counted
// vmcnt: steady-state vmcnt(8) in the out pass keeps the previous tile's 8
// output stores in flight across the barrier (only the 8 W-prefetch gl_lds
// must land; vmcnt is in-order so >=8 younger ops guarantee the oldest 8
// gl_lds are drained). Stores plain, tn-outer/tm-inner: per row each wave
// writes 256B contiguous -> two full 128B lines -> L2 write-combines
// (R3 WRITE_SIZE == ideal confirmed).
template <int STATS>
__global__ __launch_bounds__(256, 3) void gemm_pass(
    const unsigned short* __restrict__ xb,   // [NB][128] bf16
    const unsigned short* __restrict__ Wt,   // [NCPAD][128] bf16 (x log2e)
    const float* __restrict__ bias,          // [NC]
    float* __restrict__ S,                   // [NB]
    float* __restrict__ out) {               // [NB][NC]
  __shared__ __align__(16) unsigned short Xl[BT * 128];   // 16 KB
  __shared__ __align__(16) unsigned short Wl[128 * 128];  // 32 KB
  __shared__ float sS[BT];

  const int bid = blockIdx.x;
  const int slice = bid % SLICES, bt0 = (bid / SLICES) * BT;
  const int tid = threadIdx.x;
  const int w = tid >> 6, l = tid & 63;
  const int lane15 = l & 15, quad = l >> 4;
  const int wm = w >> 1, wn = w & 1;         // wm: class half, wn: batch half

  // ---- stage Xl (4 iters) + first W tile (8 iters); XOR swizzle ---------
  #pragma unroll
  for (int i = 0; i < 4; ++i) {
    int bbase = i * 256 + w * 64;            // wave-uniform 16B-block base
    int bi = bbase + l;
    int r = bi >> 4, j = bi & 15;
    int jg = j ^ (r & 15);
    __builtin_amdgcn_global_load_lds(
        (const unsigned int*)(xb + (size_t)(bt0 + r) * ND + jg * 8),
        (unsigned int*)(Xl + bbase * 8), 16, 0, 0);
  }
  #pragma unroll
  for (int i = 0; i < 8; ++i) {
    int bbase = i * 256 + w * 64;
    int bi = bbase + l;
    int r = bi >> 4, j = bi & 15;
    int jg = j ^ (r & 15);
    __builtin_amdgcn_global_load_lds(
        (const unsigned int*)(Wt + (size_t)(slice * 128 + r) * ND + jg * 8),
        (unsigned int*)(Wl + bbase * 8), 16, 0, 0);
  }
  if (!STATS) {
    if (tid < BT) sS[tid] = S[bt0 + tid];
  }

  float psum[2] = {0.f, 0.f};
  int first = 1;

  for (int ct = slice; ct < NMT; ct += SLICES) {
    const int ct0 = ct * 128;
    // bias (x log2e) for this job's 4 class quads; NC%16==0 so 16-class
    // tiles are entirely valid or entirely invalid. Issued pre-barrier.
    facc4 bias4[4]; int cvalid[4];
    #pragma unroll
    for (int tm = 0; tm < 4; ++tm) {
      int cb = ct0 + wm * 64 + tm * 16 + quad * 4;
      cvalid[tm] = (cb < NC);
      facc4 bv = cvalid[tm] ? *(const facc4*)(bias + cb)
                            : (facc4){0.f, 0.f, 0.f, 0.f};
      bias4[tm] = bv * LOG2E;
    }

    if (first) {
      // full drain: initial 12 gl_lds (+ sS publish via lgkm) -> all ready
      __syncthreads();
      first = 0;
    } else {
      // own W-prefetch (8 gl_lds) must have landed; previous tile's stores
      // (<=8, out pass only) may stay in flight. Wait BEFORE the barrier
      // so every wave's prefetch has landed once all waves pass it.
      if (STATS) {
        asm volatile("s_waitcnt vmcnt(0)" ::: "memory");
      } else {
        asm volatile("s_waitcnt vmcnt(8)" ::: "memory");
      }
      __builtin_amdgcn_sched_barrier(0);
      __builtin_amdgcn_s_barrier();
      __builtin_amdgcn_sched_barrier(0);
    }

    // ---- MFMA: 4 K-steps of 32; wave (wm,wn) owns 64x32 = 4x2 tiles ------
    facc4 acc[4][2];
    #pragma unroll
    for (int a = 0; a < 4; ++a)
      #pragma unroll
      for (int b = 0; b < 2; ++b) acc[a][b] = (facc4){0.f, 0.f, 0.f, 0.f};

    #pragma unroll
    for (int kk = 0; kk < 4; ++kk) {
      bfrag8 af[4], bf[2];
      const int jj = (kk * 4 + quad) ^ lane15;  // swizzled 16B-block in row
      #pragma unroll
      for (int tm = 0; tm < 4; ++tm)
        af[tm] = *(const bfrag8*)(Wl + (wm * 64 + tm * 16 + lane15) * 128 + jj * 8);
      #pragma unroll
      for (int tn = 0; tn < 2; ++tn)
        bf[tn] = *(const bfrag8*)(Xl + (wn * 32 + tn * 16 + lane15) * 128 + jj * 8);
      #pragma unroll
      for (int tm = 0; tm < 4; ++tm)
        #pragma unroll
        for (int tn = 0; tn < 2; ++tn)
          acc[tm][tn] = __builtin_amdgcn_mfma_f32_16x16x32_bf16(
              af[tm], bf[tn], acc[tm][tn], 0, 0, 0);
    }

    // all waves done reading Wl -> safe to restage after this barrier
    __builtin_amdgcn_sched_barrier(0);
    __builtin_amdgcn_s_barrier();
    __builtin_amdgcn_sched_barrier(0);

    // ---- issue next W tile; flies under the epilogue ---------------------
    if (ct + SLICES < NMT) {
      const int nct0 = (ct + SLICES) * 128;
      #pragma unroll
      for (int i = 0; i < 8; ++i) {
        int bbase = i * 256 + w * 64;
        int bi = bbase + l;
        int r = bi >> 4, j = bi & 15;
        int jg = j ^ (r & 15);
        __builtin_amdgcn_global_load_lds(
            (const unsigned int*)(Wt + (size_t)(nct0 + r) * ND + jg * 8),
            (unsigned int*)(Wl + bbase * 8), 16, 0, 0);
      }
    }

    // ---- epilogue: native exp2/log2 (log2e folded into Wt/bias) ----------
    if (STATS) {
      #pragma unroll
      for (int tn = 0; tn < 2; ++tn) {
        float p = 0.f;
        #pragma unroll
        for (int tm = 0; tm < 4; ++tm) {
          if (cvalid[tm]) {
            #pragma unroll
            for (int rg = 0; rg < 4; ++rg)
              p += exp2f(acc[tm][tn][rg] + bias4[tm][rg]);
          }
        }
        psum[tn] += p;
      }
    } else {
      #pragma unroll
      for (int tn = 0; tn < 2; ++tn) {
        int b = wn * 32 + tn * 16 + lane15;
        float Sv = sS[b];
        float* orow = out + (size_t)(bt0 + b) * NC;
        #pragma unroll
        for (int tm = 0; tm < 4; ++tm) {
          if (cvalid[tm]) {
            int cb = ct0 + wm * 64 + tm * 16 + quad * 4;
            facc4 o;
            #pragma unroll
            for (int rg = 0; rg < 4; ++rg) {
              float e = exp2f(acc[tm][tn][rg] + bias4[tm][rg]);
              o[rg] = NLN2 * log2f(Sv - e);
            }
            *(facc4*)(orow + cb) = o;
          }
        }
      }
    }
  }

  if (STATS) {
    #pragma unroll
    for (int tn = 0; tn < 2; ++tn) {
      float p = psum[tn];
      p += __shfl_xor(p, 16, 64);
      p += __shfl_xor(p, 32, 64);
      if (quad == 0)
        atomicAdd(&S[bt0 + wn * 32 + tn * 16 + lane15], p);
    }
  }
}

extern "C" void kernel_launch(void* const* d_in, const int* in_sizes, int n_in,
                              void* d_out, int out_size, void* d_ws, size_t ws_size,
                              hipStream_t stream) {
  const float* x    = (const float*)d_in[0];   // [8192][128]
  const float* W    = (const float*)d_in[1];   // [128][10000]
  const float* bias = (const float*)d_in[2];   // [10000]
  float* out = (float*)d_out;

  char* ws = (char*)d_ws;
  unsigned short* xb = (unsigned short*)ws;                          // 2 MB
  unsigned short* Wt = (unsigned short*)(ws + (size_t)NB * ND * 2);  // 2.53 MB
  float* S = (float*)(ws + (size_t)NB * ND * 2 + (size_t)NCPAD * ND * 2);

  prep_kernel<<<XJOBS + SJOBS + WJOBS, 256, 0, stream>>>(x, W, xb, Wt, S);
  gemm_pass<1><<<GRID, 256, 0, stream>>>(xb, Wt, bias, S, nullptr);
  gemm_pass<0><<<GRID, 256, 0, stream>>>(xb, Wt, bias, S, out);
}